// Round 10
// baseline (3887.034 us; speedup 1.0000x reference)
//
#include <hip/hip_runtime.h>

// Problem constants
// B=64, T=512, Lc=16, DW=300, CD=50, NF=100, KS=3, H=256, K=9, CV=100
// x dim = DW+NF = 400 ; gates = 4H = 1024

__device__ __forceinline__ float sigf(float x){ return 1.0f/(1.0f + expf(-x)); }

// ---------------- pack weights ----------------
__global__ void pack_weights(const float* __restrict__ Wih_f, const float* __restrict__ Wih_b,
                             const float* __restrict__ Whh_f, const float* __restrict__ Whh_b,
                             const float* __restrict__ fin_W,
                             float4* __restrict__ Wp_f, float4* __restrict__ Wp_b,
                             float4* __restrict__ WT_f, float4* __restrict__ WT_b,
                             float* __restrict__ finWT){
  int stride = gridDim.x*blockDim.x;
  for (int idx = blockIdx.x*blockDim.x + threadIdx.x; idx < 425872; idx += stride){
    if (idx < 204800){
      int i2 = idx; const float* W = Wih_f; float4* P = Wp_f;
      if (i2 >= 102400){ i2 -= 102400; W = Wih_b; P = Wp_b; }
      int d = i2 >> 8, j = i2 & 255;
      P[i2] = make_float4(W[j*400+d], W[(j+256)*400+d], W[(j+512)*400+d], W[(j+768)*400+d]);
    } else if (idx < 335872){
      int i2 = idx - 204800; const float* W = Whh_f; float4* P = WT_f;
      if (i2 >= 65536){ i2 -= 65536; W = Whh_b; P = WT_b; }
      int d = i2 >> 8, j = i2 & 255;
      P[i2] = make_float4(W[j*256+d], W[(j+256)*256+d], W[(j+512)*256+d], W[(j+768)*256+d]);
    } else {
      int i2 = idx - 335872;
      int d = i2 / 300, j = i2 - d*300;
      finWT[d*304 + j] = fin_W[j*300 + d];
    }
  }
}

// ---------------- featurize: embed (WG 0..2047) + char CNN (WG 2048..6143) ----------------
__global__ __launch_bounds__(256) void featurize(const float* __restrict__ we_in,
      const float* __restrict__ finWT, const float* __restrict__ finb,
      const int* __restrict__ chars, const float* __restrict__ char_emb,
      const float* __restrict__ convW, const float* __restrict__ convb,
      float* __restrict__ x){
  __shared__ __align__(16) char fsm[31104];
  int bid = blockIdx.x;
  int tid = threadIdx.x;
  if (bid < 2048){
    // ---- embed: x[:, 0:300] ----
    float* embT = (float*)fsm;       // [300*16]
    int tok0 = bid * 16;
    for (int idx = tid; idx < 4800; idx += 256){
      int tt = idx / 300, d = idx - tt*300;
      embT[d*16 + tt] = we_in[(size_t)tok0*300 + idx];
    }
    __syncthreads();
    for (int j = tid; j < 300; j += 256){
      float bias = finb[j];
      float acc[16];
#pragma unroll
      for (int k2=0;k2<16;k2++) acc[k2]=bias;
      const float4* e4 = (const float4*)embT;
#pragma unroll 4
      for (int d=0; d<300; d++){
        float w = finWT[d*304 + j];
        float4 a = e4[d*4+0], b2 = e4[d*4+1], c2 = e4[d*4+2], d2 = e4[d*4+3];
        acc[0]+=a.x*w;  acc[1]+=a.y*w;  acc[2]+=a.z*w;  acc[3]+=a.w*w;
        acc[4]+=b2.x*w; acc[5]+=b2.y*w; acc[6]+=b2.z*w; acc[7]+=b2.w*w;
        acc[8]+=c2.x*w; acc[9]+=c2.y*w; acc[10]+=c2.z*w;acc[11]+=c2.w*w;
        acc[12]+=d2.x*w;acc[13]+=d2.y*w;acc[14]+=d2.z*w;acc[15]+=d2.w*w;
      }
#pragma unroll
      for (int k2=0;k2<16;k2++) x[(size_t)(tok0+k2)*400 + j] = acc[k2];
    }
  } else {
    // ---- char CNN: x[:, 300:400] ----
    float* ce2 = (float*)fsm;              // [8*952]
    int* chs = (int*)(fsm + 30464);        // [128]
    int tok0 = (bid - 2048) * 8;
    if (tid < 128) chs[tid] = chars[(size_t)tok0*16 + tid];
    __syncthreads();
    for (int idx = tid; idx < 7200; idx += 256){
      int tok = idx / 900; int r = idx - tok*900;
      int w1 = r / 50; int c = r - w1*50;
      float v = 0.f;
      if (w1 >= 1 && w1 <= 16) v = char_emb[chs[tok*16 + (w1-1)]*50 + c];
      ce2[tok*952 + c*19 + w1] = v;
    }
    __syncthreads();
    for (int p = tid; p < 800; p += 256){
      int tok = p / 100, f = p - tok*100;
      float s[16];
#pragma unroll
      for (int w=0; w<16; w++) s[w] = 0.f;
      const float* cebase = ce2 + tok*952;
      for (int c=0; c<50; c++){
        float cr[18];
#pragma unroll
        for (int i=0;i<18;i++) cr[i] = cebase[c*19+i];
#pragma unroll
        for (int k2=0;k2<3;k2++){
          float wv = convW[(k2*50+c)*100 + f];
#pragma unroll
          for (int w=0;w<16;w++) s[w] += cr[w+k2]*wv;
        }
      }
      float m = s[0];
#pragma unroll
      for (int w=1;w<16;w++) m = fmaxf(m, s[w]);
      m = fmaxf(0.f, m + convb[f]);
      x[(size_t)(tok0+tok)*400 + 300 + f] = m;
    }
  }
}

// ---------------- standalone input-gate GEMM (chunk 0 = 32 steps) ----------------
// tokens = 32 per batch (log2CH=5), writes into stride-128 buffer.
__global__ __launch_bounds__(256) void pre_gemm(const float* __restrict__ x,
     const float4* __restrict__ Wp_f, const float4* __restrict__ Wp_b,
     const float* __restrict__ b_f, const float* __restrict__ b_b,
     const int* __restrict__ lengths,
     float4* __restrict__ pre_f, float4* __restrict__ pre_b,
     int t0, int log2CH){
  int dir = blockIdx.z;
  const float4* Wp = dir ? Wp_b : Wp_f;
  const float* bias = dir ? b_b : b_f;
  float4* pre = dir ? pre_b : pre_f;
  int tok0 = blockIdx.x * 64;
  int j0 = blockIdx.y * 64;
  __shared__ float As[16][68];
  __shared__ float4 Bs[4][16][16];
  __shared__ int rows_s[64];
  int tid = threadIdx.x;
  int tx = tid & 15, ty = tid >> 4;
  int chm = (1 << log2CH) - 1;
  if (tid < 64){
    int tok = tok0 + tid;
    int b = tok >> log2CH;
    int trel = tok & chm;
    int t = t0 + trel;
    int row;
    if (dir == 0) row = t;
    else { int len = lengths[b]; int pr = len - 1 - t; row = pr < 0 ? 0 : pr; }
    rows_s[tid] = b*512 + row;
  }
  float4 acc[4][4];
#pragma unroll
  for (int s2=0;s2<4;s2++){
    int j = j0 + tx*4 + s2;
    float4 bj = make_float4(bias[j], bias[j+256], bias[j+512], bias[j+768]);
#pragma unroll
    for (int r=0;r<4;r++) acc[r][s2] = bj;
  }
  __syncthreads();
  int tokA = tid >> 2, kqA = tid & 3;
  int jjB = tid & 63,  kbB = tid >> 6;
  float4 aReg; float4 bReg[4];
  {
    aReg = *(const float4*)&x[(size_t)rows_s[tokA]*400 + 0 + kqA*4];
#pragma unroll
    for (int rr=0;rr<4;rr++) bReg[rr] = Wp[(size_t)(0 + kbB + rr*4)*256 + j0 + jjB];
  }
  for (int kt=0; kt<25; ++kt){
    As[kqA*4+0][tokA] = aReg.x;
    As[kqA*4+1][tokA] = aReg.y;
    As[kqA*4+2][tokA] = aReg.z;
    As[kqA*4+3][tokA] = aReg.w;
#pragma unroll
    for (int rr=0;rr<4;rr++) Bs[jjB&3][kbB+rr*4][jjB>>2] = bReg[rr];
    __syncthreads();
    if (kt < 24){
      int k0n = (kt+1)*16;
      aReg = *(const float4*)&x[(size_t)rows_s[tokA]*400 + k0n + kqA*4];
#pragma unroll
      for (int rr=0;rr<4;rr++) bReg[rr] = Wp[(size_t)(k0n + kbB + rr*4)*256 + j0 + jjB];
    }
#pragma unroll
    for (int kk=0; kk<16; ++kk){
      float a[4];
#pragma unroll
      for (int r=0;r<4;r++) a[r] = As[kk][ty*4+r];
#pragma unroll
      for (int s2=0;s2<4;s2++){
        float4 b4 = Bs[s2][kk][tx];
#pragma unroll
        for (int r=0;r<4;r++){
          acc[r][s2].x += a[r]*b4.x;
          acc[r][s2].y += a[r]*b4.y;
          acc[r][s2].z += a[r]*b4.z;
          acc[r][s2].w += a[r]*b4.w;
        }
      }
    }
    __syncthreads();
  }
#pragma unroll
  for (int r=0;r<4;r++){
    int tok = tok0 + ty*4 + r;
    int bb = tok >> log2CH;
    int tr = tok & chm;
#pragma unroll
    for (int s2=0;s2<4;s2++){
      pre[(size_t)(bb*128 + tr)*256 + j0 + tx*4 + s2] = acc[r][s2];
    }
  }
}

// ---------------- fused: scan (WG 0..127) + next-chunk pre-GEMM (WG 128..255) ----
#define NRD 24
#define NLD 8
#define NSTREAM (64 - NRD - NLD)   // 32

// LDS pool offsets (bytes)
#define OFF_WLDS 0
#define OFF_PART 131072
#define OFF_OWS  143360
#define OFF_H    152576
#define POOL_SZ  154624
// pre-branch per-group layout (groups of 256 threads)
#define PG_AS    0          // float As[16][68]  = 4352 B
#define PG_BS    4352       // float4 Bs[16][32] = 8192 B
#define PG_ROWS  12544      // int rows[64]      = 256 B
#define PG_STRIDE 12800

__global__ __attribute__((amdgpu_num_vgpr(128))) __launch_bounds__(1024, 1)
void fused_scan_pre(const float4* __restrict__ prec_f, const float4* __restrict__ prec_b,
     const float4* __restrict__ pren_f, float4* __restrict__ pren_f_w,
     float4* __restrict__ pren_b_w,
     const float4* __restrict__ WT_f, const float4* __restrict__ WT_b,
     const float4* __restrict__ Wp_f, const float4* __restrict__ Wp_b,
     const float* __restrict__ b_f, const float* __restrict__ b_b,
     const float* __restrict__ x, const int* __restrict__ lengths,
     const float* __restrict__ outW,
     float* __restrict__ logits_f, float* __restrict__ logits_b,
     float* __restrict__ st_h, float* __restrict__ st_c,
     int t0, int nsteps, int t0n, int do_pre){
  __shared__ __align__(16) char smem[POOL_SZ];
  int wid = blockIdx.x;
  int tid = threadIdx.x;
  if (wid < 128){
    // ================= scan branch =================
    int dir = wid & 1;
    int b = wid >> 1;
    int len = lengths[b];
    if (len <= t0) return;
    const float4* pre = (dir ? prec_b : prec_f) + (size_t)b*128*256;
    const float4* WT = dir ? WT_b : WT_f;
    float* lg = (dir ? logits_b : logits_f) + (size_t)b*512*9;
    float4* wlds = (float4*)(smem + OFF_WLDS);   // [q*8+l][256]
    float4* part = (float4*)(smem + OFF_PART);   // [768]
    float*  oWs  = (float*)(smem + OFF_OWS);     // [2304]
    float*  hbuf = (float*)(smem + OFF_H);       // [512] double-buffered h
    int j = tid & 255, q = tid >> 8;
    for (int i = tid; i < 2304; i += 1024) oWs[i] = outW[dir*2304 + i];
    for (int i = tid; i < 4*NLD*256; i += 1024){
      int qq = i >> 11;
      int rr = i & (NLD*256 - 1);
      int dl = rr >> 8, jj = rr & 255;
      wlds[(qq*NLD + dl)*256 + jj] = WT[(size_t)(qq*64 + NRD + dl)*256 + jj];
    }
    const float4* WTq = WT + (size_t)q*64*256;
    float4 wreg[NRD];
#pragma unroll
    for (int r=0; r<NRD; ++r) wreg[r] = WTq[(size_t)r*256 + j];
    float c = 0.f;
    if (t0 == 0){
      if (tid < 256) hbuf[tid] = 0.f;
    } else {
      if (tid < 256) hbuf[tid] = st_h[(dir*64+b)*256 + tid];
      if (q == 0) c = st_c[(dir*64+b)*256 + j];
    }
    __syncthreads();
    int tend = len < t0+nsteps ? len : t0+nsteps;
    const float4* WTs = WTq + (size_t)(NRD+NLD)*256 + j;
    int cur = 0;
    for (int t=t0; t<tend; ++t){
      const float* hc = hbuf + (cur << 8);
      const float* hq = hc + (q << 6);
      float4 p0;
      if (q == 0) p0 = pre[(size_t)(t - t0)*256 + j];
      float4 acc = make_float4(0.f,0.f,0.f,0.f);
#pragma unroll 8
      for (int s=0; s<NSTREAM; ++s){
        float hv = hq[NRD+NLD+s];
        float4 w = WTs[(size_t)s*256];
        acc.x += w.x*hv; acc.y += w.y*hv; acc.z += w.z*hv; acc.w += w.w*hv;
      }
#pragma unroll
      for (int r=0; r<NRD; ++r){
        float hv = hq[r];
        float4 w = wreg[r];
        acc.x += w.x*hv; acc.y += w.y*hv; acc.z += w.z*hv; acc.w += w.w*hv;
      }
#pragma unroll
      for (int l=0; l<NLD; ++l){
        float hv = hq[NRD+l];
        float4 w = wlds[(q*NLD + l)*256 + j];
        acc.x += w.x*hv; acc.y += w.y*hv; acc.z += w.z*hv; acc.w += w.w*hv;
      }
      if (q) part[((q-1)<<8) + j] = acc;
      // logits of previous h (reads hc; overlaps)
      if (t > t0 && tid < 576){
        int pprev = dir ? (len - t) : (t - 1);
        int k = tid >> 6, l = tid & 63;
        float s = hc[l]*oWs[l*9+k] + hc[l+64]*oWs[(l+64)*9+k]
                + hc[l+128]*oWs[(l+128)*9+k] + hc[l+192]*oWs[(l+192)*9+k];
#pragma unroll
        for (int o=32; o; o>>=1) s += __shfl_down(s, o, 64);
        if (l == 0) lg[pprev*9 + k] = s;
      }
      __syncthreads();                    // B: hc reads done, partials visible
      if (q == 0){
        float4 p1 = part[j], p2 = part[256+j], p3 = part[512+j];
        float gi = acc.x + p0.x + p1.x + p2.x + p3.x;
        float gf = acc.y + p0.y + p1.y + p2.y + p3.y;
        float gg = acc.z + p0.z + p1.z + p2.z + p3.z;
        float go = acc.w + p0.w + p1.w + p2.w + p3.w;
        c = sigf(gf)*c + sigf(gi)*tanhf(gg);
        float h = sigf(go)*tanhf(c);
        hbuf[((cur^1)<<8) + j] = h;
      }
      __syncthreads();                    // C: new h visible
      cur ^= 1;
    }
    // epilogue: logits for final h of chunk
    const float* hc = hbuf + (cur << 8);
    if (tid < 576){
      int plast = dir ? (len - tend) : (tend - 1);
      int k = tid >> 6, l = tid & 63;
      float s = hc[l]*oWs[l*9+k] + hc[l+64]*oWs[(l+64)*9+k]
              + hc[l+128]*oWs[(l+128)*9+k] + hc[l+192]*oWs[(l+192)*9+k];
#pragma unroll
      for (int o=32; o; o>>=1) s += __shfl_down(s, o, 64);
      if (l == 0) lg[plast*9 + k] = s;
    }
    if (tid < 256) st_h[(dir*64+b)*256 + tid] = hc[tid];
    if (q == 0) st_c[(dir*64+b)*256 + j] = c;
  } else {
    // ================= pre branch: compute chunk t0n (128 tokens/batch, clamped) =====
    if (!do_pre) return;
    int w = wid - 128;
    int g = tid >> 8, lt = tid & 255;
    char* gp = smem + g*PG_STRIDE;
    float (*As)[68] = (float(*)[68])(gp + PG_AS);
    float4* Bsl = (float4*)(gp + PG_BS);          // [16][32] -> kk*32+u
    int* rows = (int*)(gp + PG_ROWS);
    int tx = lt & 15, ty4 = (lt >> 4) * 4;
    int tokA = lt >> 2, kqA = lt & 3;
    int uB = lt & 31, kbB = lt >> 5;
    for (int s=0; s<4; ++s){
      int tix = s*512 + g*128 + w;                // [0,2048)
      int dir = tix & 1;
      int jh = (tix >> 1) & 7;                    // 32-unit group
      int tokT = tix >> 4;                        // [0,128)
      int j0u = jh * 32;
      int tok0 = tokT * 64;
      const float4* Wp = dir ? Wp_b : Wp_f;
      const float* bias = dir ? b_b : b_f;
      float4* pren = dir ? pren_b_w : pren_f_w;
      __syncthreads();                            // previous tile done
      if (lt < 64){
        int tok = tok0 + lt;
        int bb = tok >> 7, trel = tok & 127;
        int t = t0n + trel; if (t > 511) t = 511;
        int row;
        if (dir == 0) row = t;
        else { int len = lengths[bb]; int pr = len - 1 - t; row = pr < 0 ? 0 : pr; }
        rows[lt] = bb*512 + row;
      }
      float4 acc[4][2];
#pragma unroll
      for (int s2=0;s2<2;s2++){
        int u = j0u + tx + s2*16;
        float4 bj = make_float4(bias[u], bias[u+256], bias[u+512], bias[u+768]);
#pragma unroll
        for (int r=0;r<4;r++) acc[r][s2] = bj;
      }
      __syncthreads();                            // rows visible
      for (int kt=0; kt<25; ++kt){
        int k0 = kt*16;
        {
          const float* xr = x + (size_t)rows[tokA]*400 + k0 + kqA*4;
          float4 av = *(const float4*)xr;
          As[kqA*4+0][tokA]=av.x; As[kqA*4+1][tokA]=av.y;
          As[kqA*4+2][tokA]=av.z; As[kqA*4+3][tokA]=av.w;
          Bsl[kbB*32 + uB]     = Wp[(size_t)(k0+kbB)*256 + j0u + uB];
          Bsl[(kbB+8)*32 + uB] = Wp[(size_t)(k0+kbB+8)*256 + j0u + uB];
        }
        __syncthreads();                          // staged
#pragma unroll 4
        for (int kk=0; kk<16; ++kk){
          float a0 = As[kk][ty4+0], a1 = As[kk][ty4+1], a2 = As[kk][ty4+2], a3 = As[kk][ty4+3];
          float4 b0 = Bsl[kk*32 + tx], b1 = Bsl[kk*32 + tx + 16];
          acc[0][0].x += a0*b0.x; acc[0][0].y += a0*b0.y; acc[0][0].z += a0*b0.z; acc[0][0].w += a0*b0.w;
          acc[1][0].x += a1*b0.x; acc[1][0].y += a1*b0.y; acc[1][0].z += a1*b0.z; acc[1][0].w += a1*b0.w;
          acc[2][0].x += a2*b0.x; acc[2][0].y += a2*b0.y; acc[2][0].z += a2*b0.z; acc[2][0].w += a2*b0.w;
          acc[3][0].x += a3*b0.x; acc[3][0].y += a3*b0.y; acc[3][0].z += a3*b0.z; acc[3][0].w += a3*b0.w;
          acc[0][1].x += a0*b1.x; acc[0][1].y += a0*b1.y; acc[0][1].z += a0*b1.z; acc[0][1].w += a0*b1.w;
          acc[1][1].x += a1*b1.x; acc[1][1].y += a1*b1.y; acc[1][1].z += a1*b1.z; acc[1][1].w += a1*b1.w;
          acc[2][1].x += a2*b1.x; acc[2][1].y += a2*b1.y; acc[2][1].z += a2*b1.z; acc[2][1].w += a2*b1.w;
          acc[3][1].x += a3*b1.x; acc[3][1].y += a3*b1.y; acc[3][1].z += a3*b1.z; acc[3][1].w += a3*b1.w;
        }
        __syncthreads();                          // compute done before restage
      }
#pragma unroll
      for (int r=0;r<4;r++){
        int tok = tok0 + ty4 + r;
        pren[(size_t)tok*256 + j0u + tx]      = acc[r][0];
        pren[(size_t)tok*256 + j0u + tx + 16] = acc[r][1];
      }
    }
  }
}

// ---------------- merged CRF forward + Viterbi ----------------
__global__ __launch_bounds__(64) void crf_viterbi_kernel(const float* __restrict__ logits_f,
     const float* __restrict__ logits_b, const float* __restrict__ outb_,
     const int* __restrict__ tags, const int* __restrict__ lengths,
     const float* __restrict__ trans, const float* __restrict__ start_trans,
     const float* __restrict__ end_trans, float* __restrict__ loss_partial,
     float* __restrict__ preds){
  int wid = blockIdx.x;
  int is_crf = wid < 64 ? 1 : 0;
  int b = is_crf ? wid : wid - 64;
  int len = lengths[b];
  int tid = threadIdx.x;
  __shared__ float e_s[4608];
  __shared__ float tr[81];
  __shared__ float alpha[9];
  __shared__ int tg[512];
  __shared__ unsigned char bp[4608];
  const float* lf = logits_f + (size_t)b*4608;
  const float* lb = logits_b + (size_t)b*4608;
  for (int i=tid; i<4608; i+=64){
    int k = i - (i/9)*9;
    e_s[i] = lf[i] + lb[i] + outb_[k];
  }
  for (int i=tid; i<81; i+=64) tr[i] = trans[i];
  if (is_crf){
    for (int i=tid; i<512; i+=64) tg[i] = tags[b*512 + i];
    __syncthreads();
    if (tid < 9) alpha[tid] = start_trans[tid] + e_s[tid];
    __syncthreads();
    for (int t=1; t<len; ++t){
      float nxt = 0.f;
      if (tid < 9){
        float v[9];
#pragma unroll
        for (int j2=0;j2<9;j2++) v[j2] = alpha[j2] + tr[j2*9+tid];
        float m = v[0];
#pragma unroll
        for (int j2=1;j2<9;j2++) m = fmaxf(m, v[j2]);
        float ssum = 0.f;
#pragma unroll
        for (int j2=0;j2<9;j2++) ssum += expf(v[j2]-m);
        nxt = m + logf(ssum) + e_s[t*9+tid];
      }
      __syncthreads();
      if (tid < 9) alpha[tid] = nxt;
      __syncthreads();
    }
    if (tid == 0){
      float m = alpha[0] + end_trans[0];
      for (int k2=1;k2<9;k2++) m = fmaxf(m, alpha[k2]+end_trans[k2]);
      float ssum = 0.f;
      for (int k2=0;k2<9;k2++) ssum += expf(alpha[k2]+end_trans[k2]-m);
      float Z = m + logf(ssum);
      int prev = tg[0];
      float sc = start_trans[prev] + e_s[prev];
      for (int t=1;t<len;++t){
        int cur = tg[t];
        sc += tr[prev*9+cur] + e_s[t*9+cur];
        prev = cur;
      }
      sc += end_trans[prev];
      loss_partial[b] = Z - sc;
    }
  } else {
    __syncthreads();
    if (tid < 9) alpha[tid] = start_trans[tid] + e_s[tid];
    __syncthreads();
    for (int t=1; t<len; ++t){
      float nxt = 0.f; int bj = 0;
      if (tid < 9){
        float m = alpha[0] + tr[tid];
#pragma unroll
        for (int j2=1;j2<9;j2++){
          float v = alpha[j2] + tr[j2*9+tid];
          if (v > m){ m = v; bj = j2; }
        }
        nxt = m + e_s[t*9+tid];
      }
      __syncthreads();
      if (tid < 9){ alpha[tid] = nxt; bp[t*9+tid] = (unsigned char)bj; }
      __syncthreads();
    }
    for (int p2 = len + tid; p2 < 512; p2 += 64) preds[(size_t)b*512 + p2] = 0.f;
    if (tid == 0){
      float m = alpha[0] + end_trans[0]; int last = 0;
      for (int k2=1;k2<9;k2++){
        float v = alpha[k2] + end_trans[k2];
        if (v > m){ m = v; last = k2; }
      }
      int cur = last;
      preds[(size_t)b*512 + (len-1)] = (float)cur;
      for (int p2 = len-2; p2 >= 0; --p2){
        cur = bp[(p2+1)*9 + cur];
        preds[(size_t)b*512 + p2] = (float)cur;
      }
    }
  }
}

// ---------------- loss reduction ----------------
__global__ void loss_sum_kernel(const float* __restrict__ lp, float* __restrict__ out){
  float v = lp[threadIdx.x];
#pragma unroll
  for (int o=32; o; o>>=1) v += __shfl_down(v, o, 64);
  if (threadIdx.x == 0) out[0] = v;
}

extern "C" void kernel_launch(void* const* d_in, const int* in_sizes, int n_in,
                              void* d_out, int out_size, void* d_ws, size_t ws_size,
                              hipStream_t stream) {
  const float* word_embs  = (const float*)d_in[0];
  const int*   chars      = (const int*)  d_in[1];
  const int*   lengths    = (const int*)  d_in[2];
  const int*   tags       = (const int*)  d_in[3];
  const float* fin_W      = (const float*)d_in[4];
  const float* fin_b      = (const float*)d_in[5];
  const float* char_emb   = (const float*)d_in[6];
  const float* conv_W     = (const float*)d_in[7];
  const float* conv_b     = (const float*)d_in[8];
  const float* Wih_f      = (const float*)d_in[9];
  const float* Whh_f      = (const float*)d_in[10];
  const float* b_f        = (const float*)d_in[11];
  const float* Wih_b      = (const float*)d_in[12];
  const float* Whh_b      = (const float*)d_in[13];
  const float* b_b        = (const float*)d_in[14];
  const float* out_W      = (const float*)d_in[15];
  const float* out_b      = (const float*)d_in[16];
  const float* trans      = (const float*)d_in[17];
  const float* start_tr   = (const float*)d_in[18];
  const float* end_tr     = (const float*)d_in[19];

  float* ws = (float*)d_ws;
  float*  x         = ws;                        // 13,107,200
  float4* Wp_f      = (float4*)(ws + 13107200);  //    409,600 floats
  float4* Wp_b      = (float4*)(ws + 13516800);  //    409,600
  float4* WT_f      = (float4*)(ws + 13926400);  //    262,144
  float4* WT_b      = (float4*)(ws + 14188544);  //    262,144
  float*  finWT     = ws + 14450688;             //     91,200
  float*  logits_f  = ws + 14541888;             //    294,912
  float*  logits_b  = ws + 14836800;             //    294,912
  float*  st_h      = ws + 15131712;             //     32,768
  float*  st_c      = ws + 15164480;             //     32,768
  float*  loss_part = ws + 15197248;             //         64
  const size_t FIXED_F = 15197312;
  // ping-pong pre buffers: 64 batches x 128 tokens x 1024 gates (as float4: x256)
  float4* preA_f = (float4*)(ws + FIXED_F);
  float4* preA_b = preA_f + (size_t)64*128*256;
  float4* preB_f = preA_b + (size_t)64*128*256;
  float4* preB_b = preB_f + (size_t)64*128*256;

  float* out = (float*)d_out;

  pack_weights<<<1664, 256, 0, stream>>>(Wih_f, Wih_b, Whh_f, Whh_b, fin_W,
                                         Wp_f, Wp_b, WT_f, WT_b, finWT);
  featurize<<<6144, 256, 0, stream>>>(word_embs, finWT, fin_b, chars, char_emb,
                                      conv_W, conv_b, x);

  // chunk 0: [0,32) into buffer A (standalone, small)
  pre_gemm<<<dim3(32, 4, 2), 256, 0, stream>>>(x, Wp_f, Wp_b, b_f, b_b, lengths,
                                               preA_f, preA_b, 0, 5);
  // F0: scan [0,32) from A    | pre [32,160)  -> B
  fused_scan_pre<<<256, 1024, 0, stream>>>(preA_f, preA_b, preB_f, preB_f, preB_b,
      WT_f, WT_b, Wp_f, Wp_b, b_f, b_b, x, lengths, out_W,
      logits_f, logits_b, st_h, st_c, 0, 32, 32, 1);
  // F1: scan [32,160) from B  | pre [160,288) -> A
  fused_scan_pre<<<256, 1024, 0, stream>>>(preB_f, preB_b, preA_f, preA_f, preA_b,
      WT_f, WT_b, Wp_f, Wp_b, b_f, b_b, x, lengths, out_W,
      logits_f, logits_b, st_h, st_c, 32, 128, 160, 1);
  // F2: scan [160,288) from A | pre [288,416) -> B
  fused_scan_pre<<<256, 1024, 0, stream>>>(preA_f, preA_b, preB_f, preB_f, preB_b,
      WT_f, WT_b, Wp_f, Wp_b, b_f, b_b, x, lengths, out_W,
      logits_f, logits_b, st_h, st_c, 160, 128, 288, 1);
  // F3: scan [288,416) from B | pre [416,512) -> A (computed as 128 toks, clamped)
  fused_scan_pre<<<256, 1024, 0, stream>>>(preB_f, preB_b, preA_f, preA_f, preA_b,
      WT_f, WT_b, Wp_f, Wp_b, b_f, b_b, x, lengths, out_W,
      logits_f, logits_b, st_h, st_c, 288, 128, 416, 1);
  // F4: scan [416,512) from A | no pre
  fused_scan_pre<<<256, 1024, 0, stream>>>(preA_f, preA_b, preB_f, preB_f, preB_b,
      WT_f, WT_b, Wp_f, Wp_b, b_f, b_b, x, lengths, out_W,
      logits_f, logits_b, st_h, st_c, 416, 96, 0, 0);

  crf_viterbi_kernel<<<128, 64, 0, stream>>>(logits_f, logits_b, out_b, tags, lengths,
                                             trans, start_tr, end_tr, loss_part, out + 1);
  loss_sum_kernel<<<1, 64, 0, stream>>>(loss_part, out);
}

// Round 11
// 3819.690 us; speedup vs baseline: 1.0176x; 1.0176x over previous
//
#include <hip/hip_runtime.h>

// Problem constants
// B=64, T=512, Lc=16, DW=300, CD=50, NF=100, KS=3, H=256, K=9, CV=100
// x dim = DW+NF = 400 ; gates = 4H = 1024

__device__ __forceinline__ float sigf(float x){ return 1.0f/(1.0f + expf(-x)); }

// ---------------- pack weights ----------------
__global__ void pack_weights(const float* __restrict__ Wih_f, const float* __restrict__ Wih_b,
                             const float* __restrict__ Whh_f, const float* __restrict__ Whh_b,
                             const float* __restrict__ fin_W,
                             float4* __restrict__ Wp_f, float4* __restrict__ Wp_b,
                             float4* __restrict__ WT_f, float4* __restrict__ WT_b,
                             float* __restrict__ finWT){
  int stride = gridDim.x*blockDim.x;
  for (int idx = blockIdx.x*blockDim.x + threadIdx.x; idx < 425872; idx += stride){
    if (idx < 204800){
      int i2 = idx; const float* W = Wih_f; float4* P = Wp_f;
      if (i2 >= 102400){ i2 -= 102400; W = Wih_b; P = Wp_b; }
      int d = i2 >> 8, j = i2 & 255;
      P[i2] = make_float4(W[j*400+d], W[(j+256)*400+d], W[(j+512)*400+d], W[(j+768)*400+d]);
    } else if (idx < 335872){
      int i2 = idx - 204800; const float* W = Whh_f; float4* P = WT_f;
      if (i2 >= 65536){ i2 -= 65536; W = Whh_b; P = WT_b; }
      int d = i2 >> 8, j = i2 & 255;
      P[i2] = make_float4(W[j*256+d], W[(j+256)*256+d], W[(j+512)*256+d], W[(j+768)*256+d]);
    } else {
      int i2 = idx - 335872;
      int d = i2 / 300, j = i2 - d*300;
      finWT[d*304 + j] = fin_W[j*300 + d];
    }
  }
}

// ---------------- featurize: embed (WG 0..2047) + char CNN (WG 2048..6143) ----------------
__global__ __launch_bounds__(256) void featurize(const float* __restrict__ we_in,
      const float* __restrict__ finWT, const float* __restrict__ finb,
      const int* __restrict__ chars, const float* __restrict__ char_emb,
      const float* __restrict__ convW, const float* __restrict__ convb,
      float* __restrict__ x){
  __shared__ __align__(16) char fsm[31104];
  int bid = blockIdx.x;
  int tid = threadIdx.x;
  if (bid < 2048){
    // ---- embed: x[:, 0:300] ----
    float* embT = (float*)fsm;       // [300*16]
    int tok0 = bid * 16;
    for (int idx = tid; idx < 4800; idx += 256){
      int tt = idx / 300, d = idx - tt*300;
      embT[d*16 + tt] = we_in[(size_t)tok0*300 + idx];
    }
    __syncthreads();
    for (int j = tid; j < 300; j += 256){
      float bias = finb[j];
      float acc[16];
#pragma unroll
      for (int k2=0;k2<16;k2++) acc[k2]=bias;
      const float4* e4 = (const float4*)embT;
#pragma unroll 4
      for (int d=0; d<300; d++){
        float w = finWT[d*304 + j];
        float4 a = e4[d*4+0], b2 = e4[d*4+1], c2 = e4[d*4+2], d2 = e4[d*4+3];
        acc[0]+=a.x*w;  acc[1]+=a.y*w;  acc[2]+=a.z*w;  acc[3]+=a.w*w;
        acc[4]+=b2.x*w; acc[5]+=b2.y*w; acc[6]+=b2.z*w; acc[7]+=b2.w*w;
        acc[8]+=c2.x*w; acc[9]+=c2.y*w; acc[10]+=c2.z*w;acc[11]+=c2.w*w;
        acc[12]+=d2.x*w;acc[13]+=d2.y*w;acc[14]+=d2.z*w;acc[15]+=d2.w*w;
      }
#pragma unroll
      for (int k2=0;k2<16;k2++) x[(size_t)(tok0+k2)*400 + j] = acc[k2];
    }
  } else {
    // ---- char CNN: x[:, 300:400] ----
    float* ce2 = (float*)fsm;              // [8*952]
    int* chs = (int*)(fsm + 30464);        // [128]
    int tok0 = (bid - 2048) * 8;
    if (tid < 128) chs[tid] = chars[(size_t)tok0*16 + tid];
    __syncthreads();
    for (int idx = tid; idx < 7200; idx += 256){
      int tok = idx / 900; int r = idx - tok*900;
      int w1 = r / 50; int c = r - w1*50;
      float v = 0.f;
      if (w1 >= 1 && w1 <= 16) v = char_emb[chs[tok*16 + (w1-1)]*50 + c];
      ce2[tok*952 + c*19 + w1] = v;
    }
    __syncthreads();
    for (int p = tid; p < 800; p += 256){
      int tok = p / 100, f = p - tok*100;
      float s[16];
#pragma unroll
      for (int w=0; w<16; w++) s[w] = 0.f;
      const float* cebase = ce2 + tok*952;
      for (int c=0; c<50; c++){
        float cr[18];
#pragma unroll
        for (int i=0;i<18;i++) cr[i] = cebase[c*19+i];
#pragma unroll
        for (int k2=0;k2<3;k2++){
          float wv = convW[(k2*50+c)*100 + f];
#pragma unroll
          for (int w=0;w<16;w++) s[w] += cr[w+k2]*wv;
        }
      }
      float m = s[0];
#pragma unroll
      for (int w=1;w<16;w++) m = fmaxf(m, s[w]);
      m = fmaxf(0.f, m + convb[f]);
      x[(size_t)(tok0+tok)*400 + 300 + f] = m;
    }
  }
}

// ---------------- standalone input-gate GEMM (chunk 0, arbitrary CH) ----------------
// grid.x = CH (64 tokens each, total 64*CH tokens), writes stride-128 buffer.
__global__ __launch_bounds__(256) void pre_gemm(const float* __restrict__ x,
     const float4* __restrict__ Wp_f, const float4* __restrict__ Wp_b,
     const float* __restrict__ b_f, const float* __restrict__ b_b,
     const int* __restrict__ lengths,
     float4* __restrict__ pre_f, float4* __restrict__ pre_b,
     int t0, int CH){
  int dir = blockIdx.z;
  const float4* Wp = dir ? Wp_b : Wp_f;
  const float* bias = dir ? b_b : b_f;
  float4* pre = dir ? pre_b : pre_f;
  int tok0 = blockIdx.x * 64;
  int j0 = blockIdx.y * 64;
  __shared__ float As[16][68];
  __shared__ float4 Bs[4][16][16];
  __shared__ int rows_s[64];
  __shared__ int poss_s[64];
  int tid = threadIdx.x;
  int tx = tid & 15, ty = tid >> 4;
  if (tid < 64){
    int tok = tok0 + tid;
    int b = tok / CH;
    int trel = tok - b*CH;
    int t = t0 + trel;
    int row;
    if (dir == 0) row = t;
    else { int len = lengths[b]; int pr = len - 1 - t; row = pr < 0 ? 0 : pr; }
    rows_s[tid] = b*512 + row;
    poss_s[tid] = b*128 + trel;
  }
  float4 acc[4][4];
#pragma unroll
  for (int s2=0;s2<4;s2++){
    int j = j0 + tx*4 + s2;
    float4 bj = make_float4(bias[j], bias[j+256], bias[j+512], bias[j+768]);
#pragma unroll
    for (int r=0;r<4;r++) acc[r][s2] = bj;
  }
  __syncthreads();
  int tokA = tid >> 2, kqA = tid & 3;
  int jjB = tid & 63,  kbB = tid >> 6;
  float4 aReg; float4 bReg[4];
  {
    aReg = *(const float4*)&x[(size_t)rows_s[tokA]*400 + 0 + kqA*4];
#pragma unroll
    for (int rr=0;rr<4;rr++) bReg[rr] = Wp[(size_t)(0 + kbB + rr*4)*256 + j0 + jjB];
  }
  for (int kt=0; kt<25; ++kt){
    As[kqA*4+0][tokA] = aReg.x;
    As[kqA*4+1][tokA] = aReg.y;
    As[kqA*4+2][tokA] = aReg.z;
    As[kqA*4+3][tokA] = aReg.w;
#pragma unroll
    for (int rr=0;rr<4;rr++) Bs[jjB&3][kbB+rr*4][jjB>>2] = bReg[rr];
    __syncthreads();
    if (kt < 24){
      int k0n = (kt+1)*16;
      aReg = *(const float4*)&x[(size_t)rows_s[tokA]*400 + k0n + kqA*4];
#pragma unroll
      for (int rr=0;rr<4;rr++) bReg[rr] = Wp[(size_t)(k0n + kbB + rr*4)*256 + j0 + jjB];
    }
#pragma unroll
    for (int kk=0; kk<16; ++kk){
      float4 a4 = *(const float4*)&As[kk][ty*4];   // one b128 instead of 4x b32
      float a[4] = {a4.x, a4.y, a4.z, a4.w};
#pragma unroll
      for (int s2=0;s2<4;s2++){
        float4 b4 = Bs[s2][kk][tx];
#pragma unroll
        for (int r=0;r<4;r++){
          acc[r][s2].x += a[r]*b4.x;
          acc[r][s2].y += a[r]*b4.y;
          acc[r][s2].z += a[r]*b4.z;
          acc[r][s2].w += a[r]*b4.w;
        }
      }
    }
    __syncthreads();
  }
#pragma unroll
  for (int r=0;r<4;r++){
    int pp = poss_s[ty*4+r];
#pragma unroll
    for (int s2=0;s2<4;s2++){
      pre[(size_t)pp*256 + j0 + tx*4 + s2] = acc[r][s2];
    }
  }
}

// ---------------- fused: scan (WG 0..127) + next-chunk pre-GEMM (WG 128..255) ----
#define NRD 24
#define NLD 8
#define NSTREAM (64 - NRD - NLD)   // 32

// LDS pool offsets (bytes)
#define OFF_WLDS 0
#define OFF_PART 131072
#define OFF_OWS  143360
#define OFF_H    152576
#define POOL_SZ  154624
// pre-branch per-group layout (groups of 256 threads)
#define PG_AS    0          // float As[16][68]  = 4352 B
#define PG_BS    4352       // float4 Bs[16][32] = 8192 B
#define PG_ROWS  12544      // int rows[64]+poss[64] = 512 B
#define PG_STRIDE 13056

__global__ __launch_bounds__(1024, 1)
void fused_scan_pre(const float4* __restrict__ prec_f, const float4* __restrict__ prec_b,
     float4* __restrict__ pren_f_w, float4* __restrict__ pren_b_w,
     const float4* __restrict__ WT_f, const float4* __restrict__ WT_b,
     const float4* __restrict__ Wp_f, const float4* __restrict__ Wp_b,
     const float* __restrict__ b_f, const float* __restrict__ b_b,
     const float* __restrict__ x, const int* __restrict__ lengths,
     const float* __restrict__ outW,
     float* __restrict__ logits_f, float* __restrict__ logits_b,
     float* __restrict__ st_h, float* __restrict__ st_c,
     int t0, int nsteps, int t0n, int cnext, int do_pre){
  __shared__ __align__(16) char smem[POOL_SZ];
  int wid = blockIdx.x;
  int tid = threadIdx.x;
  if (wid < 128){
    // ================= scan branch =================
    int dir = wid & 1;
    int b = wid >> 1;
    int len = lengths[b];
    if (len <= t0) return;
    const float4* pre = (dir ? prec_b : prec_f) + (size_t)b*128*256;
    const float4* WT = dir ? WT_b : WT_f;
    float* lg = (dir ? logits_b : logits_f) + (size_t)b*512*9;
    float4* wlds = (float4*)(smem + OFF_WLDS);   // [q*8+l][256]
    float4* part = (float4*)(smem + OFF_PART);   // [768]
    float*  oWs  = (float*)(smem + OFF_OWS);     // [2304]
    float*  hbuf = (float*)(smem + OFF_H);       // [512] double-buffered h
    int j = tid & 255, q = tid >> 8;
    for (int i = tid; i < 2304; i += 1024) oWs[i] = outW[dir*2304 + i];
    for (int i = tid; i < 4*NLD*256; i += 1024){
      int qq = i >> 11;
      int rr = i & (NLD*256 - 1);
      int dl = rr >> 8, jj = rr & 255;
      wlds[(qq*NLD + dl)*256 + jj] = WT[(size_t)(qq*64 + NRD + dl)*256 + jj];
    }
    const float4* WTq = WT + (size_t)q*64*256;
    float4 wreg[NRD];
#pragma unroll
    for (int r=0; r<NRD; ++r) wreg[r] = WTq[(size_t)r*256 + j];
    float c = 0.f;
    if (t0 == 0){
      if (tid < 256) hbuf[tid] = 0.f;
    } else {
      if (tid < 256) hbuf[tid] = st_h[(dir*64+b)*256 + tid];
      if (q == 0) c = st_c[(dir*64+b)*256 + j];
    }
    __syncthreads();
    int tend = len < t0+nsteps ? len : t0+nsteps;
    const float4* WTs = WTq + (size_t)(NRD+NLD)*256 + j;
    int cur = 0;
    for (int t=t0; t<tend; ++t){
      const float* hc = hbuf + (cur << 8);
      const float* hq = hc + (q << 6);
      float4 p0;
      if (q == 0) p0 = pre[(size_t)(t - t0)*256 + j];
      float4 acc = make_float4(0.f,0.f,0.f,0.f);
#pragma unroll 8
      for (int s=0; s<NSTREAM; ++s){
        float hv = hq[NRD+NLD+s];
        float4 w = WTs[(size_t)s*256];
        acc.x += w.x*hv; acc.y += w.y*hv; acc.z += w.z*hv; acc.w += w.w*hv;
      }
#pragma unroll
      for (int r=0; r<NRD; ++r){
        float hv = hq[r];
        float4 w = wreg[r];
        acc.x += w.x*hv; acc.y += w.y*hv; acc.z += w.z*hv; acc.w += w.w*hv;
      }
#pragma unroll
      for (int l=0; l<NLD; ++l){
        float hv = hq[NRD+l];
        float4 w = wlds[(q*NLD + l)*256 + j];
        acc.x += w.x*hv; acc.y += w.y*hv; acc.z += w.z*hv; acc.w += w.w*hv;
      }
      if (q) part[((q-1)<<8) + j] = acc;
      // logits of previous h (reads hc; overlaps)
      if (t > t0 && tid < 576){
        int pprev = dir ? (len - t) : (t - 1);
        int k = tid >> 6, l = tid & 63;
        float s = hc[l]*oWs[l*9+k] + hc[l+64]*oWs[(l+64)*9+k]
                + hc[l+128]*oWs[(l+128)*9+k] + hc[l+192]*oWs[(l+192)*9+k];
#pragma unroll
        for (int o=32; o; o>>=1) s += __shfl_down(s, o, 64);
        if (l == 0) lg[pprev*9 + k] = s;
      }
      __syncthreads();                    // B: hc reads done, partials visible
      if (q == 0){
        float4 p1 = part[j], p2 = part[256+j], p3 = part[512+j];
        float gi = acc.x + p0.x + p1.x + p2.x + p3.x;
        float gf = acc.y + p0.y + p1.y + p2.y + p3.y;
        float gg = acc.z + p0.z + p1.z + p2.z + p3.z;
        float go = acc.w + p0.w + p1.w + p2.w + p3.w;
        c = sigf(gf)*c + sigf(gi)*tanhf(gg);
        float h = sigf(go)*tanhf(c);
        hbuf[((cur^1)<<8) + j] = h;
      }
      __syncthreads();                    // C: new h visible
      cur ^= 1;
    }
    // epilogue: logits for final h of chunk
    const float* hc = hbuf + (cur << 8);
    if (tid < 576){
      int plast = dir ? (len - tend) : (tend - 1);
      int k = tid >> 6, l = tid & 63;
      float s = hc[l]*oWs[l*9+k] + hc[l+64]*oWs[(l+64)*9+k]
              + hc[l+128]*oWs[(l+128)*9+k] + hc[l+192]*oWs[(l+192)*9+k];
#pragma unroll
      for (int o=32; o; o>>=1) s += __shfl_down(s, o, 64);
      if (l == 0) lg[plast*9 + k] = s;
    }
    if (tid < 256) st_h[(dir*64+b)*256 + tid] = hc[tid];
    if (q == 0) st_c[(dir*64+b)*256 + j] = c;
  } else {
    // ================= pre branch: compute chunk [t0n, t0n+cnext) =====
    if (!do_pre) return;
    int w = wid - 128;
    int g = tid >> 8, lt = tid & 255;
    char* gp = smem + g*PG_STRIDE;
    float (*As)[68] = (float(*)[68])(gp + PG_AS);
    float4* Bsl = (float4*)(gp + PG_BS);          // [16][32] -> kk*32+u
    int* rows = (int*)(gp + PG_ROWS);             // [64]
    int* poss = rows + 64;                        // [64]
    int tx = lt & 15, ty4 = (lt >> 4) * 4;
    int tokA = lt >> 2, kqA = lt & 3;
    int uB = lt & 31, kbB = lt >> 5;
    int tixmax = cnext << 4;                      // tiles*16
    int smax = (tixmax + 511) >> 9;
    for (int s=0; s<smax; ++s){
      int tix = s*512 + g*128 + w;
      bool active = tix < tixmax;
      int dir = tix & 1;
      int jh = (tix >> 1) & 7;                    // 32-unit group
      int tokT = tix >> 4;
      int j0u = jh * 32;
      int tok0 = tokT * 64;
      const float4* Wp = dir ? Wp_b : Wp_f;
      const float* bias = dir ? b_b : b_f;
      float4* pren = dir ? pren_b_w : pren_f_w;
      __syncthreads();                            // previous tile done
      if (active && lt < 64){
        int tok = tok0 + lt;
        int bb = tok / cnext;
        int trel = tok - bb*cnext;
        int t = t0n + trel;
        int row;
        if (dir == 0) row = t;
        else { int len = lengths[bb]; int pr = len - 1 - t; row = pr < 0 ? 0 : pr; }
        rows[lt] = bb*512 + row;
        poss[lt] = bb*128 + trel;
      }
      float4 acc[4][2];
#pragma unroll
      for (int s2=0;s2<2;s2++){
        int u = j0u + tx + s2*16;
        float4 bj = make_float4(bias[u], bias[u+256], bias[u+512], bias[u+768]);
#pragma unroll
        for (int r=0;r<4;r++) acc[r][s2] = bj;
      }
      __syncthreads();                            // rows visible
      for (int kt=0; kt<25; ++kt){
        int k0 = kt*16;
        if (active){
          const float* xr = x + (size_t)rows[tokA]*400 + k0 + kqA*4;
          float4 av = *(const float4*)xr;
          As[kqA*4+0][tokA]=av.x; As[kqA*4+1][tokA]=av.y;
          As[kqA*4+2][tokA]=av.z; As[kqA*4+3][tokA]=av.w;
          Bsl[kbB*32 + uB]     = Wp[(size_t)(k0+kbB)*256 + j0u + uB];
          Bsl[(kbB+8)*32 + uB] = Wp[(size_t)(k0+kbB+8)*256 + j0u + uB];
        }
        __syncthreads();                          // staged
        if (active){
#pragma unroll 4
          for (int kk=0; kk<16; ++kk){
            float4 a4 = *(const float4*)&As[kk][ty4];   // one b128
            float a0 = a4.x, a1 = a4.y, a2 = a4.z, a3 = a4.w;
            float4 b0 = Bsl[kk*32 + tx], b1 = Bsl[kk*32 + tx + 16];
            acc[0][0].x += a0*b0.x; acc[0][0].y += a0*b0.y; acc[0][0].z += a0*b0.z; acc[0][0].w += a0*b0.w;
            acc[1][0].x += a1*b0.x; acc[1][0].y += a1*b0.y; acc[1][0].z += a1*b0.z; acc[1][0].w += a1*b0.w;
            acc[2][0].x += a2*b0.x; acc[2][0].y += a2*b0.y; acc[2][0].z += a2*b0.z; acc[2][0].w += a2*b0.w;
            acc[3][0].x += a3*b0.x; acc[3][0].y += a3*b0.y; acc[3][0].z += a3*b0.z; acc[3][0].w += a3*b0.w;
            acc[0][1].x += a0*b1.x; acc[0][1].y += a0*b1.y; acc[0][1].z += a0*b1.z; acc[0][1].w += a0*b1.w;
            acc[1][1].x += a1*b1.x; acc[1][1].y += a1*b1.y; acc[1][1].z += a1*b1.z; acc[1][1].w += a1*b1.w;
            acc[2][1].x += a2*b1.x; acc[2][1].y += a2*b1.y; acc[2][1].z += a2*b1.z; acc[2][1].w += a2*b1.w;
            acc[3][1].x += a3*b1.x; acc[3][1].y += a3*b1.y; acc[3][1].z += a3*b1.z; acc[3][1].w += a3*b1.w;
          }
        }
        __syncthreads();                          // compute done before restage
      }
      if (active){
#pragma unroll
        for (int r=0;r<4;r++){
          int pp = poss[ty4 + r];
          pren[(size_t)pp*256 + j0u + tx]      = acc[r][0];
          pren[(size_t)pp*256 + j0u + tx + 16] = acc[r][1];
        }
      }
    }
  }
}

// ---------------- merged CRF forward + Viterbi ----------------
__global__ __launch_bounds__(64) void crf_viterbi_kernel(const float* __restrict__ logits_f,
     const float* __restrict__ logits_b, const float* __restrict__ outb_,
     const int* __restrict__ tags, const int* __restrict__ lengths,
     const float* __restrict__ trans, const float* __restrict__ start_trans,
     const float* __restrict__ end_trans, float* __restrict__ loss_partial,
     float* __restrict__ preds){
  int wid = blockIdx.x;
  int is_crf = wid < 64 ? 1 : 0;
  int b = is_crf ? wid : wid - 64;
  int len = lengths[b];
  int tid = threadIdx.x;
  __shared__ float e_s[4608];
  __shared__ float tr[81];
  __shared__ float alpha[9];
  __shared__ int tg[512];
  __shared__ unsigned char bp[4608];
  const float* lf = logits_f + (size_t)b*4608;
  const float* lb = logits_b + (size_t)b*4608;
  for (int i=tid; i<4608; i+=64){
    int k = i - (i/9)*9;
    e_s[i] = lf[i] + lb[i] + outb_[k];
  }
  for (int i=tid; i<81; i+=64) tr[i] = trans[i];
  if (is_crf){
    for (int i=tid; i<512; i+=64) tg[i] = tags[b*512 + i];
    __syncthreads();
    if (tid < 9) alpha[tid] = start_trans[tid] + e_s[tid];
    __syncthreads();
    for (int t=1; t<len; ++t){
      float nxt = 0.f;
      if (tid < 9){
        float v[9];
#pragma unroll
        for (int j2=0;j2<9;j2++) v[j2] = alpha[j2] + tr[j2*9+tid];
        float m = v[0];
#pragma unroll
        for (int j2=1;j2<9;j2++) m = fmaxf(m, v[j2]);
        float ssum = 0.f;
#pragma unroll
        for (int j2=0;j2<9;j2++) ssum += expf(v[j2]-m);
        nxt = m + logf(ssum) + e_s[t*9+tid];
      }
      __syncthreads();
      if (tid < 9) alpha[tid] = nxt;
      __syncthreads();
    }
    if (tid == 0){
      float m = alpha[0] + end_trans[0];
      for (int k2=1;k2<9;k2++) m = fmaxf(m, alpha[k2]+end_trans[k2]);
      float ssum = 0.f;
      for (int k2=0;k2<9;k2++) ssum += expf(alpha[k2]+end_trans[k2]-m);
      float Z = m + logf(ssum);
      int prev = tg[0];
      float sc = start_trans[prev] + e_s[prev];
      for (int t=1;t<len;++t){
        int cur = tg[t];
        sc += tr[prev*9+cur] + e_s[t*9+cur];
        prev = cur;
      }
      sc += end_trans[prev];
      loss_partial[b] = Z - sc;
    }
  } else {
    __syncthreads();
    if (tid < 9) alpha[tid] = start_trans[tid] + e_s[tid];
    __syncthreads();
    for (int t=1; t<len; ++t){
      float nxt = 0.f; int bj = 0;
      if (tid < 9){
        float m = alpha[0] + tr[tid];
#pragma unroll
        for (int j2=1;j2<9;j2++){
          float v = alpha[j2] + tr[j2*9+tid];
          if (v > m){ m = v; bj = j2; }
        }
        nxt = m + e_s[t*9+tid];
      }
      __syncthreads();
      if (tid < 9){ alpha[tid] = nxt; bp[t*9+tid] = (unsigned char)bj; }
      __syncthreads();
    }
    for (int p2 = len + tid; p2 < 512; p2 += 64) preds[(size_t)b*512 + p2] = 0.f;
    if (tid == 0){
      float m = alpha[0] + end_trans[0]; int last = 0;
      for (int k2=1;k2<9;k2++){
        float v = alpha[k2] + end_trans[k2];
        if (v > m){ m = v; last = k2; }
      }
      int cur = last;
      preds[(size_t)b*512 + (len-1)] = (float)cur;
      for (int p2 = len-2; p2 >= 0; --p2){
        cur = bp[(p2+1)*9 + cur];
        preds[(size_t)b*512 + p2] = (float)cur;
      }
    }
  }
}

// ---------------- loss reduction ----------------
__global__ void loss_sum_kernel(const float* __restrict__ lp, float* __restrict__ out){
  float v = lp[threadIdx.x];
#pragma unroll
  for (int o=32; o; o>>=1) v += __shfl_down(v, o, 64);
  if (threadIdx.x == 0) out[0] = v;
}

extern "C" void kernel_launch(void* const* d_in, const int* in_sizes, int n_in,
                              void* d_out, int out_size, void* d_ws, size_t ws_size,
                              hipStream_t stream) {
  const float* word_embs  = (const float*)d_in[0];
  const int*   chars      = (const int*)  d_in[1];
  const int*   lengths    = (const int*)  d_in[2];
  const int*   tags       = (const int*)  d_in[3];
  const float* fin_W      = (const float*)d_in[4];
  const float* fin_b      = (const float*)d_in[5];
  const float* char_emb   = (const float*)d_in[6];
  const float* conv_W     = (const float*)d_in[7];
  const float* conv_b     = (const float*)d_in[8];
  const float* Wih_f      = (const float*)d_in[9];
  const float* Whh_f      = (const float*)d_in[10];
  const float* b_f        = (const float*)d_in[11];
  const float* Wih_b      = (const float*)d_in[12];
  const float* Whh_b      = (const float*)d_in[13];
  const float* b_b        = (const float*)d_in[14];
  const float* out_W      = (const float*)d_in[15];
  const float* out_b      = (const float*)d_in[16];
  const float* trans      = (const float*)d_in[17];
  const float* start_tr   = (const float*)d_in[18];
  const float* end_tr     = (const float*)d_in[19];

  float* ws = (float*)d_ws;
  float*  x         = ws;                        // 13,107,200
  float4* Wp_f      = (float4*)(ws + 13107200);  //    409,600 floats
  float4* Wp_b      = (float4*)(ws + 13516800);  //    409,600
  float4* WT_f      = (float4*)(ws + 13926400);  //    262,144
  float4* WT_b      = (float4*)(ws + 14188544);  //    262,144
  float*  finWT     = ws + 14450688;             //     91,200
  float*  logits_f  = ws + 14541888;             //    294,912
  float*  logits_b  = ws + 14836800;             //    294,912
  float*  st_h      = ws + 15131712;             //     32,768
  float*  st_c      = ws + 15164480;             //     32,768
  float*  loss_part = ws + 15197248;             //         64
  const size_t FIXED_F = 15197312;
  // ping-pong pre buffers: 64 batches x 128 token-slots x 1024 gates (as float4: x256)
  float4* preA_f = (float4*)(ws + FIXED_F);
  float4* preA_b = preA_f + (size_t)64*128*256;
  float4* preB_f = preA_b + (size_t)64*128*256;
  float4* preB_b = preB_f + (size_t)64*128*256;

  float* out = (float*)d_out;

  pack_weights<<<1664, 256, 0, stream>>>(Wih_f, Wih_b, Whh_f, Whh_b, fin_W,
                                         Wp_f, Wp_b, WT_f, WT_b, finWT);
  featurize<<<6144, 256, 0, stream>>>(word_embs, finWT, fin_b, chars, char_emb,
                                      conv_W, conv_b, x);

  // chunk 0: [0,86) into buffer A (standalone, full machine)
  pre_gemm<<<dim3(86, 4, 2), 256, 0, stream>>>(x, Wp_f, Wp_b, b_f, b_b, lengths,
                                               preA_f, preA_b, 0, 86);
  // equal chunks: {86,86,85,85,85,85} -> t0 = 0,86,172,257,342,427
  // F0: scan [0,86) from A     | pre [86,172)  -> B
  fused_scan_pre<<<256, 1024, 0, stream>>>(preA_f, preA_b, preB_f, preB_b,
      WT_f, WT_b, Wp_f, Wp_b, b_f, b_b, x, lengths, out_W,
      logits_f, logits_b, st_h, st_c, 0, 86, 86, 86, 1);
  // F1: scan [86,172) from B   | pre [172,257) -> A
  fused_scan_pre<<<256, 1024, 0, stream>>>(preB_f, preB_b, preA_f, preA_b,
      WT_f, WT_b, Wp_f, Wp_b, b_f, b_b, x, lengths, out_W,
      logits_f, logits_b, st_h, st_c, 86, 86, 172, 85, 1);
  // F2: scan [172,257) from A  | pre [257,342) -> B
  fused_scan_pre<<<256, 1024, 0, stream>>>(preA_f, preA_b, preB_f, preB_b,
      WT_f, WT_b, Wp_f, Wp_b, b_f, b_b, x, lengths, out_W,
      logits_f, logits_b, st_h, st_c, 172, 85, 257, 85, 1);
  // F3: scan [257,342) from B  | pre [342,427) -> A
  fused_scan_pre<<<256, 1024, 0, stream>>>(preB_f, preB_b, preA_f, preA_b,
      WT_f, WT_b, Wp_f, Wp_b, b_f, b_b, x, lengths, out_W,
      logits_f, logits_b, st_h, st_c, 257, 85, 342, 85, 1);
  // F4: scan [342,427) from A  | pre [427,512) -> B
  fused_scan_pre<<<256, 1024, 0, stream>>>(preA_f, preA_b, preB_f, preB_b,
      WT_f, WT_b, Wp_f, Wp_b, b_f, b_b, x, lengths, out_W,
      logits_f, logits_b, st_h, st_c, 342, 85, 427, 85, 1);
  // F5: scan [427,512) from B  | no pre
  fused_scan_pre<<<256, 1024, 0, stream>>>(preB_f, preB_b, preA_f, preA_b,
      WT_f, WT_b, Wp_f, Wp_b, b_f, b_b, x, lengths, out_W,
      logits_f, logits_b, st_h, st_c, 427, 85, 0, 85, 0);

  crf_viterbi_kernel<<<128, 64, 0, stream>>>(logits_f, logits_b, out_b, tags, lengths,
                                             trans, start_tr, end_tr, loss_part, out + 1);
  loss_sum_kernel<<<1, 64, 0, stream>>>(loss_part, out);
}